// Round 1
// baseline (1007.776 us; speedup 1.0000x reference)
//
#include <hip/hip_runtime.h>
#include <hip/hip_bf16.h>
#include <cstddef>

// Problem dims (fixed by reference): B=2, S=2048, H=1024, NH=4, DH=256
constexpr int Bx = 2, Sx = 2048, Hx = 1024, NHx = 4, DHx = 256;
constexpr int BQ = 64, BK = 64;
constexpr float RSQ = 0.0625f;   // 1/sqrt(DH) = 1/16

__device__ __forceinline__ float logsigf(float x) {
  // log(sigmoid(x)) = -log1p(exp(-x)) for x>=0 ; x - log1p(exp(x)) for x<0
  return (x >= 0.0f) ? -log1pf(expf(-x)) : x - log1pf(expf(x));
}

// ---------------- Kernel 1: gate preactivations ig/fg = [q,k,v] . W^T + b ----
__global__ __launch_bounds__(256)
void gates_kernel(const float* __restrict__ q, const float* __restrict__ k,
                  const float* __restrict__ v,
                  const float* __restrict__ wi, const float* __restrict__ bi,
                  const float* __restrict__ wf, const float* __restrict__ bf,
                  float* __restrict__ ig, float* __restrict__ fg)
{
  const int bs = blockIdx.x;           // b*S + s
  const int t  = threadIdx.x;
  float p[8] = {0,0,0,0,0,0,0,0};      // [ig h0..3, fg h0..3]
  const size_t rowoff = (size_t)bs * Hx;
  for (int idx = t; idx < 3 * Hx; idx += 256) {
    float g;
    if (idx < Hx)          g = q[rowoff + idx];
    else if (idx < 2 * Hx) g = k[rowoff + idx - Hx];
    else                   g = v[rowoff + idx - 2 * Hx];
#pragma unroll
    for (int h = 0; h < NHx; ++h) {
      p[h]     += g * wi[h * 3 * Hx + idx];
      p[4 + h] += g * wf[h * 3 * Hx + idx];
    }
  }
  __shared__ float red[8][256];
#pragma unroll
  for (int g2 = 0; g2 < 8; ++g2) red[g2][t] = p[g2];
  __syncthreads();
  for (int s2 = 128; s2 > 0; s2 >>= 1) {
    if (t < s2) {
#pragma unroll
      for (int g2 = 0; g2 < 8; ++g2) red[g2][t] += red[g2][t + s2];
    }
    __syncthreads();
  }
  if (t < 8) {
    const int h = t & 3;
    const int b = bs / Sx, spos = bs % Sx;
    const size_t o = ((size_t)(b * NHx + h)) * Sx + spos;
    if (t < 4) ig[o] = red[t][0] + bi[h];
    else       fg[o] = red[t][0] + bf[h];
  }
}

// ---------------- Kernel 2: per-(b,h) scan: a[], M[], exp(-m)[] --------------
// F[s] = cumsum(log sigmoid(fg)); a[s] = ig[s] - F[s]; M[s] = prefixmax(a);
// nf[s] = exp(-(F[s]+M[s]))  (the normalizer floor exp(-max_log_D))
__global__ __launch_bounds__(256)
void scan_kernel(const float* __restrict__ ig, const float* __restrict__ fg,
                 float* __restrict__ av, float* __restrict__ Mv,
                 float* __restrict__ nfv)
{
  const int bh = blockIdx.x;
  const int t  = threadIdx.x;
  const size_t base = (size_t)bh * Sx;
  const int s0 = t * 8;                 // 256 threads * 8 = 2048
  float4 f0 = *(const float4*)(fg + base + s0);
  float4 f1 = *(const float4*)(fg + base + s0 + 4);
  float4 g0 = *(const float4*)(ig + base + s0);
  float4 g1 = *(const float4*)(ig + base + s0 + 4);
  float xf[8] = {f0.x,f0.y,f0.z,f0.w,f1.x,f1.y,f1.z,f1.w};
  float xi[8] = {g0.x,g0.y,g0.z,g0.w,g1.x,g1.y,g1.z,g1.w};
  float ps[8];
  float run = 0.0f;
#pragma unroll
  for (int i = 0; i < 8; ++i) { run += logsigf(xf[i]); ps[i] = run; }
  __shared__ float ssum[256];
  __shared__ float smax[256];
  ssum[t] = run;
  __syncthreads();
  for (int st = 1; st < 256; st <<= 1) {      // Hillis-Steele inclusive sum
    float addv = (t >= st) ? ssum[t - st] : 0.0f;
    __syncthreads();
    ssum[t] += addv;
    __syncthreads();
  }
  const float exs = (t > 0) ? ssum[t - 1] : 0.0f;   // exclusive prefix
  float a[8], pm[8];
  float rm = -INFINITY;
#pragma unroll
  for (int i = 0; i < 8; ++i) {
    a[i] = xi[i] - (exs + ps[i]);
    rm = fmaxf(rm, a[i]);
    pm[i] = rm;
  }
  smax[t] = rm;
  __syncthreads();
  for (int st = 1; st < 256; st <<= 1) {      // Hillis-Steele inclusive max
    float mv = (t >= st) ? smax[t - st] : -INFINITY;
    __syncthreads();
    smax[t] = fmaxf(smax[t], mv);
    __syncthreads();
  }
  const float exm = (t > 0) ? smax[t - 1] : -INFINITY;
#pragma unroll
  for (int i = 0; i < 8; ++i) {
    const float M = fmaxf(exm, pm[i]);
    const float F = exs + ps[i];
    av[base + s0 + i]  = a[i];
    Mv[base + s0 + i]  = M;
    nfv[base + s0 + i] = expf(-(F + M));
  }
}

// ---------------- Kernel 3: flash mLSTM + fused groupnorm --------------------
// grid (S/BQ, B*NH), 256 thr. Thread (tr,tc): rows r0..r0+3 (tr*4), score
// cols c0..c0+3 (tc*4), PV dims d0..d0+15 (tc*16).
#define QK_ROW(RR, QV) \
  sc[RR][0] += QV.x*kv0.x + QV.y*kv1.x + QV.z*kv2.x + QV.w*kv3.x; \
  sc[RR][1] += QV.x*kv0.y + QV.y*kv1.y + QV.z*kv2.y + QV.w*kv3.y; \
  sc[RR][2] += QV.x*kv0.z + QV.y*kv1.z + QV.z*kv2.z + QV.w*kv3.z; \
  sc[RR][3] += QV.x*kv0.w + QV.y*kv1.w + QV.z*kv2.w + QV.w*kv3.w;

#define PV_ROW(RR, PJ) \
  acc[RR][ii*4+0] += PJ * vv.x; acc[RR][ii*4+1] += PJ * vv.y; \
  acc[RR][ii*4+2] += PJ * vv.z; acc[RR][ii*4+3] += PJ * vv.w;

__global__ __launch_bounds__(256)
void mlstm_flash(const float* __restrict__ q, const float* __restrict__ k,
                 const float* __restrict__ v,
                 const float* __restrict__ av, const float* __restrict__ Mv,
                 const float* __restrict__ nfv, const float* __restrict__ lnw,
                 float* __restrict__ out)
{
  __shared__ float Qs[BQ][68];        // [row][dchunk 64 + pad]
  __shared__ float KsT[64][BK + 4];   // transposed: [d][col]
  __shared__ float Ps[BQ][BK + 4];
  __shared__ float Vs[8][DHx + 8];    // V j-chunk of 8 rows
  __shared__ float a_s[BK];
  __shared__ float M_s[BQ];
  __shared__ float nf_s[BQ];

  const int bh = blockIdx.y, b = bh >> 2, h = bh & 3;
  const int ti = (int)gridDim.x - 1 - (int)blockIdx.x;  // big tiles first
  const int i0 = ti * BQ;
  const int tid = threadIdx.x;
  const int tr = tid >> 4, tc = tid & 15;
  const int r0 = tr * 4, c0 = tc * 4, d0 = tc * 16;

  const size_t hoff = ((size_t)b * Sx) * Hx + (size_t)h * DHx;
  const float* qb = q + hoff;
  const float* kb = k + hoff;
  const float* vb = v + hoff;

  if (tid < BQ) {
    M_s[tid]  = Mv[(size_t)bh * Sx + i0 + tid];
    nf_s[tid] = nfv[(size_t)bh * Sx + i0 + tid];
  }

  float acc[4][16];
#pragma unroll
  for (int rr = 0; rr < 4; ++rr)
#pragma unroll
    for (int i = 0; i < 16; ++i) acc[rr][i] = 0.0f;
  float rsum[4] = {0.0f, 0.0f, 0.0f, 0.0f};

  const int lr = tid >> 2, lc = (tid & 3) * 16;  // Q/K chunk loader map
  const int vr = tid >> 5, vd = (tid & 31) * 8;  // V chunk loader map

  float lw[16];
#pragma unroll
  for (int i = 0; i < 16; ++i) lw[i] = 1.0f + lnw[h * DHx + d0 + i];

  for (int tj = 0; tj <= ti; ++tj) {
    const int j0 = tj * BK;
    if (tid < BK) a_s[tid] = av[(size_t)bh * Sx + j0 + tid];
    float sc[4][4];
#pragma unroll
    for (int rr = 0; rr < 4; ++rr)
#pragma unroll
      for (int cc = 0; cc < 4; ++cc) sc[rr][cc] = 0.0f;

    for (int dc = 0; dc < DHx; dc += 64) {
      __syncthreads();   // prev readers of Qs/KsT done; a_s visible (iter 0)
      const float* qp = qb + (size_t)(i0 + lr) * Hx + dc + lc;
      float4 q0 = *(const float4*)(qp);
      float4 q1 = *(const float4*)(qp + 4);
      float4 q2 = *(const float4*)(qp + 8);
      float4 q3 = *(const float4*)(qp + 12);
      *(float4*)&Qs[lr][lc]      = q0;
      *(float4*)&Qs[lr][lc + 4]  = q1;
      *(float4*)&Qs[lr][lc + 8]  = q2;
      *(float4*)&Qs[lr][lc + 12] = q3;
      const float* kp = kb + (size_t)(j0 + lr) * Hx + dc + lc;
      float4 k0 = *(const float4*)(kp);
      float4 k1 = *(const float4*)(kp + 4);
      float4 k2 = *(const float4*)(kp + 8);
      float4 k3 = *(const float4*)(kp + 12);
      KsT[lc +  0][lr] = k0.x; KsT[lc +  1][lr] = k0.y;
      KsT[lc +  2][lr] = k0.z; KsT[lc +  3][lr] = k0.w;
      KsT[lc +  4][lr] = k1.x; KsT[lc +  5][lr] = k1.y;
      KsT[lc +  6][lr] = k1.z; KsT[lc +  7][lr] = k1.w;
      KsT[lc +  8][lr] = k2.x; KsT[lc +  9][lr] = k2.y;
      KsT[lc + 10][lr] = k2.z; KsT[lc + 11][lr] = k2.w;
      KsT[lc + 12][lr] = k3.x; KsT[lc + 13][lr] = k3.y;
      KsT[lc + 14][lr] = k3.z; KsT[lc + 15][lr] = k3.w;
      __syncthreads();
#pragma unroll
      for (int d = 0; d < 64; d += 4) {
        float4 qv0 = *(const float4*)&Qs[r0 + 0][d];
        float4 qv1 = *(const float4*)&Qs[r0 + 1][d];
        float4 qv2 = *(const float4*)&Qs[r0 + 2][d];
        float4 qv3 = *(const float4*)&Qs[r0 + 3][d];
        float4 kv0 = *(const float4*)&KsT[d + 0][c0];
        float4 kv1 = *(const float4*)&KsT[d + 1][c0];
        float4 kv2 = *(const float4*)&KsT[d + 2][c0];
        float4 kv3 = *(const float4*)&KsT[d + 3][c0];
        QK_ROW(0, qv0) QK_ROW(1, qv1) QK_ROW(2, qv2) QK_ROW(3, qv3)
      }
    }

    // P = qk * 1/sqrt(DH) * exp(a[j]-M[i]) with causal mask; track rowsums
#pragma unroll
    for (int rr = 0; rr < 4; ++rr) {
      const int gi = i0 + r0 + rr;
      const float m = M_s[r0 + rr];
      float pv[4];
#pragma unroll
      for (int cc = 0; cc < 4; ++cc) {
        const int gj = j0 + c0 + cc;
        float pval = 0.0f;
        if (gj <= gi) pval = sc[rr][cc] * RSQ * expf(a_s[c0 + cc] - m);
        pv[cc] = pval;
        rsum[rr] += pval;
      }
      *(float4*)&Ps[r0 + rr][c0] = make_float4(pv[0], pv[1], pv[2], pv[3]);
    }
    __syncthreads();   // Ps visible

    for (int jc = 0; jc < BK; jc += 8) {
      const float* vp = vb + (size_t)(j0 + jc + vr) * Hx + vd;
      float4 v0 = *(const float4*)(vp);
      float4 v1 = *(const float4*)(vp + 4);
      *(float4*)&Vs[vr][vd]     = v0;
      *(float4*)&Vs[vr][vd + 4] = v1;
      __syncthreads();
#pragma unroll
      for (int j = 0; j < 8; ++j) {
        const float pj0 = Ps[r0 + 0][jc + j];
        const float pj1 = Ps[r0 + 1][jc + j];
        const float pj2 = Ps[r0 + 2][jc + j];
        const float pj3 = Ps[r0 + 3][jc + j];
#pragma unroll
        for (int ii = 0; ii < 4; ++ii) {
          const float4 vv = *(const float4*)&Vs[j][d0 + ii * 4];
          PV_ROW(0, pj0) PV_ROW(1, pj1) PV_ROW(2, pj2) PV_ROW(3, pj3)
        }
      }
      __syncthreads();   // compute done before Vs overwrite next chunk
    }
  }

  // Epilogue: normalizer + MultiHeadLayerNorm (group norm over DH per head)
#pragma unroll
  for (int rr = 0; rr < 4; ++rr) {
    float rs = rsum[rr];
    rs += __shfl_xor(rs, 1); rs += __shfl_xor(rs, 2);
    rs += __shfl_xor(rs, 4); rs += __shfl_xor(rs, 8);
    const float norm = fmaxf(fabsf(rs), nf_s[r0 + rr]) + 1e-6f;
    const float inv = 1.0f / norm;
    float hv[16];
    float s1 = 0.0f, s2 = 0.0f;
#pragma unroll
    for (int i = 0; i < 16; ++i) {
      const float x = acc[rr][i] * inv;
      hv[i] = x; s1 += x; s2 += x * x;
    }
    s1 += __shfl_xor(s1, 1); s1 += __shfl_xor(s1, 2);
    s1 += __shfl_xor(s1, 4); s1 += __shfl_xor(s1, 8);
    s2 += __shfl_xor(s2, 1); s2 += __shfl_xor(s2, 2);
    s2 += __shfl_xor(s2, 4); s2 += __shfl_xor(s2, 8);
    const float mean = s1 * (1.0f / 256.0f);
    const float var  = s2 * (1.0f / 256.0f) - mean * mean;  // biased var
    const float rstd = rsqrtf(var + 1e-5f);
    float* op = out + ((size_t)b * Sx + (i0 + r0 + rr)) * Hx + h * DHx + d0;
#pragma unroll
    for (int ii = 0; ii < 4; ++ii) {
      float4 o;
      o.x = (hv[ii*4+0] - mean) * rstd * lw[ii*4+0];
      o.y = (hv[ii*4+1] - mean) * rstd * lw[ii*4+1];
      o.z = (hv[ii*4+2] - mean) * rstd * lw[ii*4+2];
      o.w = (hv[ii*4+3] - mean) * rstd * lw[ii*4+3];
      *(float4*)(op + ii * 4) = o;
    }
  }
}

extern "C" void kernel_launch(void* const* d_in, const int* in_sizes, int n_in,
                              void* d_out, int out_size, void* d_ws, size_t ws_size,
                              hipStream_t stream) {
  const float* q   = (const float*)d_in[0];
  const float* k   = (const float*)d_in[1];
  const float* v   = (const float*)d_in[2];
  const float* wi  = (const float*)d_in[3];
  const float* bi  = (const float*)d_in[4];
  const float* wf  = (const float*)d_in[5];
  const float* bf  = (const float*)d_in[6];
  const float* lnw = (const float*)d_in[7];
  float* out = (float*)d_out;
  float* ws  = (float*)d_ws;

  const int G = Bx * NHx * Sx;   // 16384
  float* ig  = ws;
  float* fg  = ws + (size_t)G;
  float* av  = ws + (size_t)2 * G;
  float* Mv  = ws + (size_t)3 * G;
  float* nfv = ws + (size_t)4 * G;

  gates_kernel<<<Bx * Sx, 256, 0, stream>>>(q, k, v, wi, bi, wf, bf, ig, fg);
  scan_kernel<<<Bx * NHx, 256, 0, stream>>>(ig, fg, av, Mv, nfv);
  dim3 g3(Sx / BQ, Bx * NHx);
  mlstm_flash<<<g3, 256, 0, stream>>>(q, k, v, av, Mv, nfv, lnw, out);
}

// Round 2
// 168.488 us; speedup vs baseline: 5.9813x; 5.9813x over previous
//
#include <hip/hip_runtime.h>
#include <hip/hip_bf16.h>
#include <cstddef>

// Dims fixed by reference: B=2, S=2048, H=1024, NH=4, DH=256
constexpr int Bx = 2, Sx = 2048, Hx = 1024, NHx = 4, DHx = 256;
constexpr float RSQ = 0.0625f;   // 1/sqrt(256)

typedef __attribute__((ext_vector_type(8))) short    bf16x8;
typedef __attribute__((ext_vector_type(4))) float    f32x4;
typedef __attribute__((ext_vector_type(4))) unsigned u32x4;

__device__ __forceinline__ float logsigf(float x) {
  return (x >= 0.0f) ? -log1pf(expf(-x)) : x - log1pf(expf(x));
}
__device__ __forceinline__ unsigned short f2bf(float x) {  // RNE f32->bf16
  unsigned u = __builtin_bit_cast(unsigned, x);
  u = (u + 0x7fffu + ((u >> 16) & 1u)) >> 16;
  return (unsigned short)u;
}
__device__ __forceinline__ unsigned pk2bf(float a, float b) {
  return (unsigned)f2bf(a) | ((unsigned)f2bf(b) << 16);
}

// ---------- K1: gates (ig/fg) + bf16 side-copies of Q,K ---------------------
__global__ __launch_bounds__(256)
void gates_kernel(const float* __restrict__ q, const float* __restrict__ k,
                  const float* __restrict__ v,
                  const float* __restrict__ wi, const float* __restrict__ bi,
                  const float* __restrict__ wf, const float* __restrict__ bf,
                  float* __restrict__ ig, float* __restrict__ fg,
                  unsigned short* __restrict__ Qb, unsigned short* __restrict__ Kb)
{
  const int bs = blockIdx.x;           // b*S + s
  const int t  = threadIdx.x;
  const int b = bs >> 11, spos = bs & 2047;
  float p[8] = {0,0,0,0,0,0,0,0};
  const size_t rowoff = (size_t)bs * Hx;
  for (int idx = t; idx < 3 * Hx; idx += 256) {
    float gv;
    if (idx < Hx) {
      gv = q[rowoff + idx];
      Qb[((size_t)(b * NHx + (idx >> 8)) * Sx + spos) * DHx + (idx & 255)] = f2bf(gv);
    } else if (idx < 2 * Hx) {
      gv = k[rowoff + idx - Hx];
      int kd = idx - Hx;
      Kb[((size_t)(b * NHx + (kd >> 8)) * Sx + spos) * DHx + (kd & 255)] = f2bf(gv);
    } else {
      gv = v[rowoff + idx - 2 * Hx];
    }
#pragma unroll
    for (int h = 0; h < NHx; ++h) {
      p[h]     += gv * wi[h * 3 * Hx + idx];
      p[4 + h] += gv * wf[h * 3 * Hx + idx];
    }
  }
  __shared__ float red[8][256];
#pragma unroll
  for (int g2 = 0; g2 < 8; ++g2) red[g2][t] = p[g2];
  __syncthreads();
  for (int s2 = 128; s2 > 0; s2 >>= 1) {
    if (t < s2) {
#pragma unroll
      for (int g2 = 0; g2 < 8; ++g2) red[g2][t] += red[g2][t + s2];
    }
    __syncthreads();
  }
  if (t < 8) {
    const int h = t & 3;
    const size_t o = ((size_t)(b * NHx + h)) * Sx + spos;
    if (t < 4) ig[o] = red[t][0] + bi[h];
    else       fg[o] = red[t][0] + bf[h];
  }
}

// ---------- K2: per-(b,h) scan: a[], M[], exp(-m)[] -------------------------
__global__ __launch_bounds__(256)
void scan_kernel(const float* __restrict__ ig, const float* __restrict__ fg,
                 float* __restrict__ av, float* __restrict__ Mv,
                 float* __restrict__ nfv)
{
  const int bh = blockIdx.x;
  const int t  = threadIdx.x;
  const size_t base = (size_t)bh * Sx;
  const int s0 = t * 8;
  float4 f0 = *(const float4*)(fg + base + s0);
  float4 f1 = *(const float4*)(fg + base + s0 + 4);
  float4 g0 = *(const float4*)(ig + base + s0);
  float4 g1 = *(const float4*)(ig + base + s0 + 4);
  float xf[8] = {f0.x,f0.y,f0.z,f0.w,f1.x,f1.y,f1.z,f1.w};
  float xi[8] = {g0.x,g0.y,g0.z,g0.w,g1.x,g1.y,g1.z,g1.w};
  float ps[8];
  float run = 0.0f;
#pragma unroll
  for (int i = 0; i < 8; ++i) { run += logsigf(xf[i]); ps[i] = run; }
  __shared__ float ssum[256];
  __shared__ float smax[256];
  ssum[t] = run;
  __syncthreads();
  for (int st = 1; st < 256; st <<= 1) {
    float addv = (t >= st) ? ssum[t - st] : 0.0f;
    __syncthreads();
    ssum[t] += addv;
    __syncthreads();
  }
  const float exs = (t > 0) ? ssum[t - 1] : 0.0f;
  float a[8], pm[8];
  float rm = -INFINITY;
#pragma unroll
  for (int i = 0; i < 8; ++i) {
    a[i] = xi[i] - (exs + ps[i]);
    rm = fmaxf(rm, a[i]);
    pm[i] = rm;
  }
  smax[t] = rm;
  __syncthreads();
  for (int st = 1; st < 256; st <<= 1) {
    float mv = (t >= st) ? smax[t - st] : -INFINITY;
    __syncthreads();
    smax[t] = fmaxf(smax[t], mv);
    __syncthreads();
  }
  const float exm = (t > 0) ? smax[t - 1] : -INFINITY;
#pragma unroll
  for (int i = 0; i < 8; ++i) {
    const float M = fmaxf(exm, pm[i]);
    const float F = exs + ps[i];
    av[base + s0 + i]  = a[i];
    Mv[base + s0 + i]  = M;
    nfv[base + s0 + i] = expf(-(F + M));
  }
}

// ---------- K3: V -> bf16 transposed global Vt[bh][d][s] --------------------
__global__ __launch_bounds__(256)
void vtrans_kernel(const float* __restrict__ v, unsigned short* __restrict__ vt)
{
  __shared__ float tile[64][68];
  const int st0 = blockIdx.x * 64, dt0 = blockIdx.y * 64;
  const int bh = blockIdx.z, b = bh >> 2, h = bh & 3;
  const int t = threadIdx.x;
#pragma unroll
  for (int i = 0; i < 4; ++i) {
    int u = t + 256 * i;
    int r = u >> 4, c4 = (u & 15) * 4;
    const float* p = v + ((size_t)(b * Sx) + st0 + r) * Hx + h * DHx + dt0 + c4;
    float4 vv = *(const float4*)p;
    tile[r][c4] = vv.x; tile[r][c4+1] = vv.y; tile[r][c4+2] = vv.z; tile[r][c4+3] = vv.w;
  }
  __syncthreads();
#pragma unroll
  for (int i = 0; i < 4; ++i) {
    int u = t + 256 * i;
    int dr = u >> 4, c4 = (u & 15) * 4;
    ushort4 o;
    o.x = f2bf(tile[c4+0][dr]); o.y = f2bf(tile[c4+1][dr]);
    o.z = f2bf(tile[c4+2][dr]); o.w = f2bf(tile[c4+3][dr]);
    *(ushort4*)(vt + ((size_t)bh * DHx + dt0 + dr) * Sx + st0 + c4) = o;
  }
}

// ---------- K4: flash mLSTM on MFMA ------------------------------------------
// Block: 256 thr = 4 waves; wave w owns q-rows i0+16w..+15. BK=32 keys/iter.
// Swapped QK^T: st = mfma(A=K-frag, B=Q-frag) -> S^T tile (keys x q).
// PV swapped:   accT = mfma(A=V^T-frag, B=P^T-frag) -> O^T (dims x q).
constexpr int KSTR = 272;  // K LDS row stride (bf16 elems), 32 rows
constexpr int VSTR = 40;   // Vt LDS row stride, 256 rows x 32 keys

__device__ __forceinline__ int koff(int key, int d) {
  return key * KSTR + ((((d >> 3) ^ ((key >> 2) & 7))) << 3) + (d & 7);
}
__device__ __forceinline__ int voff(int d, int k) {
  return d * VSTR + ((((k >> 3) ^ (d & 3)) & 3) << 3) + (k & 7);
}

__global__ __launch_bounds__(256, 2)
void mlstm_mfma(const unsigned short* __restrict__ Qb,
                const unsigned short* __restrict__ Kb,
                const unsigned short* __restrict__ Vt,
                const float* __restrict__ av, const float* __restrict__ Mv,
                const float* __restrict__ nfv, const float* __restrict__ lnw,
                float* __restrict__ out)
{
  __shared__ unsigned short Kls[32 * KSTR];   // 17408 B
  __shared__ unsigned short Vls[256 * VSTR];  // 20480 B

  const int bh = blockIdx.y, b = bh >> 2, h = bh & 3;
  const int ti = (int)gridDim.x - 1 - (int)blockIdx.x;   // big tiles first
  const int i0 = ti * 64;
  const int tid = threadIdx.x;
  const int w = tid >> 6, l = tid & 63;
  const int g = l >> 4, lq = l & 15;
  const int qrow = i0 + w * 16 + lq;
  const size_t bhS = (size_t)bh * Sx;

  // Q B-frags in registers (8 x bf16x8)
  bf16x8 qf[8];
  {
    const unsigned short* qp = Qb + (bhS + qrow) * DHx + g * 8;
#pragma unroll
    for (int kk = 0; kk < 8; ++kk)
      qf[kk] = *(const bf16x8*)(qp + kk * 32);
  }
  const float M  = Mv[bhS + qrow];
  const float nf = nfv[bhS + qrow];

  f32x4 acc[16];
#pragma unroll
  for (int jt = 0; jt < 16; ++jt) acc[jt] = f32x4{0, 0, 0, 0};
  float rsum = 0.f;

  const int ntiles = 2 * ti + 2;      // BK=32 tiles covering keys [0, i0+64)
  for (int tj = 0; tj < ntiles; ++tj) {
    const int j0 = tj * 32;
    __syncthreads();
    // stage K tile (32 x 256 bf16)
    {
      const unsigned short* kp = Kb + (bhS + j0) * DHx;
#pragma unroll
      for (int i = 0; i < 8; ++i) {
        int u = tid + 256 * i;
        int key = u >> 6, d = (u & 63) * 4;
        ushort4 kv = *(const ushort4*)(kp + key * DHx + d);
        *(ushort4*)&Kls[koff(key, d)] = kv;
      }
      const unsigned short* vp = Vt + (size_t)bh * DHx * Sx + j0;
#pragma unroll
      for (int i = 0; i < 8; ++i) {
        int u = tid + 256 * i;
        int d = u >> 3, kx = (u & 7) * 4;
        ushort4 vv = *(const ushort4*)(vp + (size_t)d * Sx + kx);
        *(ushort4*)&Vls[voff(d, kx)] = vv;
      }
    }
    f32x4 a4_0 = *(const f32x4*)(av + bhS + j0 + g * 4);
    f32x4 a4_1 = *(const f32x4*)(av + bhS + j0 + 16 + g * 4);
    __syncthreads();

    // QK^T swapped: st[kt] over 2 key-subtiles
    f32x4 st0 = {0,0,0,0}, st1 = {0,0,0,0};
    {
      const int kr0 = lq, kr1 = 16 + lq;
#pragma unroll
      for (int kk = 0; kk < 8; ++kk) {
        int d = kk * 32 + g * 8;
        bf16x8 kf0 = *(const bf16x8*)&Kls[koff(kr0, d)];
        st0 = __builtin_amdgcn_mfma_f32_16x16x32_bf16(kf0, qf[kk], st0, 0, 0, 0);
        bf16x8 kf1 = *(const bf16x8*)&Kls[koff(kr1, d)];
        st1 = __builtin_amdgcn_mfma_f32_16x16x32_bf16(kf1, qf[kk], st1, 0, 0, 0);
      }
    }

    // P transform (mask + decay + rsum) then bf16 pack + lane redistribution
    unsigned x0[4], x1[4];
#pragma unroll
    for (int kt = 0; kt < 2; ++kt) {
      f32x4 s = kt ? st1 : st0;
      f32x4 a = kt ? a4_1 : a4_0;
      const int kb = j0 + kt * 16 + 4 * g;
      float p0 = (kb + 0 <= qrow) ? s[0] * (RSQ * __expf(a[0] - M)) : 0.f;
      float p1 = (kb + 1 <= qrow) ? s[1] * (RSQ * __expf(a[1] - M)) : 0.f;
      float p2 = (kb + 2 <= qrow) ? s[2] * (RSQ * __expf(a[2] - M)) : 0.f;
      float p3 = (kb + 3 <= qrow) ? s[3] * (RSQ * __expf(a[3] - M)) : 0.f;
      rsum += (p0 + p1) + (p2 + p3);
      unsigned lo = pk2bf(p0, p1), hi = pk2bf(p2, p3);
      unsigned plo = __shfl_xor(lo, 16), phi = __shfl_xor(hi, 16);
      bool ge = ((g & 1) == 0);
      unsigned* x = kt ? x1 : x0;
      x[0] = ge ? lo : plo;  x[1] = ge ? hi : phi;
      x[2] = ge ? plo : lo;  x[3] = ge ? phi : hi;
    }
    unsigned pw0, pw1, pw2, pw3;
#pragma unroll
    for (int j = 0; j < 4; ++j) {
      unsigned yA = __shfl_xor(x0[j], 32);
      unsigned yB = __shfl_xor(x1[j], 32);
      unsigned r = (g == 0) ? x0[j] : (g == 1) ? yA : (g == 2) ? yB : x1[j];
      if (j == 0) pw0 = r; else if (j == 1) pw1 = r; else if (j == 2) pw2 = r; else pw3 = r;
    }
    u32x4 w4 = {pw0, pw1, pw2, pw3};
    bf16x8 pb = __builtin_bit_cast(bf16x8, w4);

    // PV swapped: acc[jt] (O^T) += mfma(V^T frag, P^T frag)
    {
      const int kx = g * 8;
#pragma unroll
      for (int jt = 0; jt < 16; ++jt) {
        bf16x8 vf = *(const bf16x8*)&Vls[voff(jt * 16 + lq, kx)];
        acc[jt] = __builtin_amdgcn_mfma_f32_16x16x32_bf16(vf, pb, acc[jt], 0, 0, 0);
      }
    }
  }

  // Epilogue: normalizer + MultiHeadLayerNorm, all cross-lane via shfl
  float rs = rsum;
  rs += __shfl_xor(rs, 16); rs += __shfl_xor(rs, 32);
  const float inv = 1.f / (fmaxf(fabsf(rs), nf) + 1e-6f);
  float s1 = 0.f, s2 = 0.f;
#pragma unroll
  for (int jt = 0; jt < 16; ++jt) {
#pragma unroll
    for (int r = 0; r < 4; ++r) {
      float xx = acc[jt][r] * inv;
      s1 += xx; s2 += xx * xx;
    }
  }
  s1 += __shfl_xor(s1, 16); s1 += __shfl_xor(s1, 32);
  s2 += __shfl_xor(s2, 16); s2 += __shfl_xor(s2, 32);
  const float mean = s1 * (1.f / 256.f);
  const float var  = s2 * (1.f / 256.f) - mean * mean;
  const float rstd = rsqrtf(var + 1e-5f);
  float* op = out + ((size_t)b * Sx + qrow) * Hx + h * DHx;
#pragma unroll
  for (int jt = 0; jt < 16; ++jt) {
    const int dbase = jt * 16 + 4 * g;
    f32x4 lw = *(const f32x4*)(lnw + h * DHx + dbase);
    float4 o;
    o.x = (acc[jt][0] * inv - mean) * rstd * (1.f + lw[0]);
    o.y = (acc[jt][1] * inv - mean) * rstd * (1.f + lw[1]);
    o.z = (acc[jt][2] * inv - mean) * rstd * (1.f + lw[2]);
    o.w = (acc[jt][3] * inv - mean) * rstd * (1.f + lw[3]);
    *(float4*)(op + dbase) = o;
  }
}

extern "C" void kernel_launch(void* const* d_in, const int* in_sizes, int n_in,
                              void* d_out, int out_size, void* d_ws, size_t ws_size,
                              hipStream_t stream) {
  const float* q   = (const float*)d_in[0];
  const float* k   = (const float*)d_in[1];
  const float* v   = (const float*)d_in[2];
  const float* wi  = (const float*)d_in[3];
  const float* bi  = (const float*)d_in[4];
  const float* wf  = (const float*)d_in[5];
  const float* bf  = (const float*)d_in[6];
  const float* lnw = (const float*)d_in[7];
  float* out = (float*)d_out;
  float* ws  = (float*)d_ws;

  const int G = Bx * NHx * Sx;         // 16384
  float* ig  = ws;
  float* fg  = ws + (size_t)G;
  float* av  = ws + (size_t)2 * G;
  float* Mv  = ws + (size_t)3 * G;
  float* nfv = ws + (size_t)4 * G;
  unsigned short* Qb = (unsigned short*)(ws + (size_t)5 * G);
  unsigned short* Kb = Qb + (size_t)Bx * Sx * Hx;   // 4,194,304 elems
  unsigned short* Vt = Kb + (size_t)Bx * Sx * Hx;
  // total ws use: 320 KB + 3 * 8 MB ~= 24.3 MB

  gates_kernel<<<Bx * Sx, 256, 0, stream>>>(q, k, v, wi, bi, wf, bf, ig, fg, Qb, Kb);
  scan_kernel<<<Bx * NHx, 256, 0, stream>>>(ig, fg, av, Mv, nfv);
  dim3 gT(Sx / 64, DHx / 64, Bx * NHx);
  vtrans_kernel<<<gT, 256, 0, stream>>>(v, Vt);
  dim3 g4(Sx / 64, Bx * NHx);
  mlstm_mfma<<<g4, 256, 0, stream>>>(Qb, Kb, Vt, av, Mv, nfv, lnw, out);
}

// Round 3
// 155.190 us; speedup vs baseline: 6.4938x; 1.0857x over previous
//
#include <hip/hip_runtime.h>
#include <hip/hip_bf16.h>
#include <cstddef>

// Dims fixed by reference: B=2, S=2048, H=1024, NH=4, DH=256
constexpr int Bx = 2, Sx = 2048, Hx = 1024, NHx = 4, DHx = 256;
constexpr float RSQ = 0.0625f;   // 1/sqrt(256)

typedef __attribute__((ext_vector_type(8))) short    bf16x8;
typedef __attribute__((ext_vector_type(4))) float    f32x4;

__device__ __forceinline__ float logsigf(float x) {
  return (x >= 0.0f) ? -log1pf(expf(-x)) : x - log1pf(expf(x));
}
__device__ __forceinline__ unsigned short f2bf(float x) {  // RNE f32->bf16
  unsigned u = __builtin_bit_cast(unsigned, x);
  u = (u + 0x7fffu + ((u >> 16) & 1u)) >> 16;
  return (unsigned short)u;
}
__device__ __forceinline__ unsigned pk2bf(float a, float b) {
  return (unsigned)f2bf(a) | ((unsigned)f2bf(b) << 16);
}

// ---------- K1: gates (ig/fg) + bf16 side-copies of Q,K ---------------------
__global__ __launch_bounds__(256)
void gates_kernel(const float* __restrict__ q, const float* __restrict__ k,
                  const float* __restrict__ v,
                  const float* __restrict__ wi, const float* __restrict__ bi,
                  const float* __restrict__ wf, const float* __restrict__ bf,
                  float* __restrict__ ig, float* __restrict__ fg,
                  unsigned short* __restrict__ Qb, unsigned short* __restrict__ Kb)
{
  const int bs = blockIdx.x;           // b*S + s
  const int t  = threadIdx.x;
  const int b = bs >> 11, spos = bs & 2047;
  float p[8] = {0,0,0,0,0,0,0,0};
  const size_t rowoff = (size_t)bs * Hx;
  for (int idx = t; idx < 3 * Hx; idx += 256) {
    float gv;
    if (idx < Hx) {
      gv = q[rowoff + idx];
      Qb[((size_t)(b * NHx + (idx >> 8)) * Sx + spos) * DHx + (idx & 255)] = f2bf(gv);
    } else if (idx < 2 * Hx) {
      gv = k[rowoff + idx - Hx];
      int kd = idx - Hx;
      Kb[((size_t)(b * NHx + (kd >> 8)) * Sx + spos) * DHx + (kd & 255)] = f2bf(gv);
    } else {
      gv = v[rowoff + idx - 2 * Hx];
    }
#pragma unroll
    for (int h = 0; h < NHx; ++h) {
      p[h]     += gv * wi[h * 3 * Hx + idx];
      p[4 + h] += gv * wf[h * 3 * Hx + idx];
    }
  }
  __shared__ float red[8][256];
#pragma unroll
  for (int g2 = 0; g2 < 8; ++g2) red[g2][t] = p[g2];
  __syncthreads();
  for (int s2 = 128; s2 > 0; s2 >>= 1) {
    if (t < s2) {
#pragma unroll
      for (int g2 = 0; g2 < 8; ++g2) red[g2][t] += red[g2][t + s2];
    }
    __syncthreads();
  }
  if (t < 8) {
    const int h = t & 3;
    const size_t o = ((size_t)(b * NHx + h)) * Sx + spos;
    if (t < 4) ig[o] = red[t][0] + bi[h];
    else       fg[o] = red[t][0] + bf[h];
  }
}

// ---------- K2: per-(b,h) scan: a[], M[], exp(-m)[] -------------------------
__global__ __launch_bounds__(256)
void scan_kernel(const float* __restrict__ ig, const float* __restrict__ fg,
                 float* __restrict__ av, float* __restrict__ Mv,
                 float* __restrict__ nfv)
{
  const int bh = blockIdx.x;
  const int t  = threadIdx.x;
  const size_t base = (size_t)bh * Sx;
  const int s0 = t * 8;
  float4 f0 = *(const float4*)(fg + base + s0);
  float4 f1 = *(const float4*)(fg + base + s0 + 4);
  float4 g0 = *(const float4*)(ig + base + s0);
  float4 g1 = *(const float4*)(ig + base + s0 + 4);
  float xf[8] = {f0.x,f0.y,f0.z,f0.w,f1.x,f1.y,f1.z,f1.w};
  float xi[8] = {g0.x,g0.y,g0.z,g0.w,g1.x,g1.y,g1.z,g1.w};
  float ps[8];
  float run = 0.0f;
#pragma unroll
  for (int i = 0; i < 8; ++i) { run += logsigf(xf[i]); ps[i] = run; }
  __shared__ float ssum[256];
  __shared__ float smax[256];
  ssum[t] = run;
  __syncthreads();
  for (int st = 1; st < 256; st <<= 1) {
    float addv = (t >= st) ? ssum[t - st] : 0.0f;
    __syncthreads();
    ssum[t] += addv;
    __syncthreads();
  }
  const float exs = (t > 0) ? ssum[t - 1] : 0.0f;
  float a[8], pm[8];
  float rm = -INFINITY;
#pragma unroll
  for (int i = 0; i < 8; ++i) {
    a[i] = xi[i] - (exs + ps[i]);
    rm = fmaxf(rm, a[i]);
    pm[i] = rm;
  }
  smax[t] = rm;
  __syncthreads();
  for (int st = 1; st < 256; st <<= 1) {
    float mv = (t >= st) ? smax[t - st] : -INFINITY;
    __syncthreads();
    smax[t] = fmaxf(smax[t], mv);
    __syncthreads();
  }
  const float exm = (t > 0) ? smax[t - 1] : -INFINITY;
#pragma unroll
  for (int i = 0; i < 8; ++i) {
    const float M = fmaxf(exm, pm[i]);
    const float F = exs + ps[i];
    av[base + s0 + i]  = a[i];
    Mv[base + s0 + i]  = M;
    nfv[base + s0 + i] = expf(-(F + M));
  }
}

// ---------- K3: V -> bf16 transposed global Vt[bh][d][s] --------------------
__global__ __launch_bounds__(256)
void vtrans_kernel(const float* __restrict__ v, unsigned short* __restrict__ vt)
{
  __shared__ float tile[64][68];
  const int st0 = blockIdx.x * 64, dt0 = blockIdx.y * 64;
  const int bh = blockIdx.z, b = bh >> 2, h = bh & 3;
  const int t = threadIdx.x;
#pragma unroll
  for (int i = 0; i < 4; ++i) {
    int u = t + 256 * i;
    int r = u >> 4, c4 = (u & 15) * 4;
    const float* p = v + ((size_t)(b * Sx) + st0 + r) * Hx + h * DHx + dt0 + c4;
    float4 vv = *(const float4*)p;
    tile[r][c4] = vv.x; tile[r][c4+1] = vv.y; tile[r][c4+2] = vv.z; tile[r][c4+3] = vv.w;
  }
  __syncthreads();
#pragma unroll
  for (int i = 0; i < 4; ++i) {
    int u = t + 256 * i;
    int dr = u >> 4, c4 = (u & 15) * 4;
    ushort4 o;
    o.x = f2bf(tile[c4+0][dr]); o.y = f2bf(tile[c4+1][dr]);
    o.z = f2bf(tile[c4+2][dr]); o.w = f2bf(tile[c4+3][dr]);
    *(ushort4*)(vt + ((size_t)bh * DHx + dt0 + dr) * Sx + st0 + c4) = o;
  }
}

// ---------- K4: flash mLSTM on MFMA, direct-L2 fragments ---------------------
// 512 thr = 8 waves. Block: 64 q-rows (tile ti), iterate BK=64 key tiles.
// QK: wave (ks=w&3, qh=w>>2): 16-key slice x 32-q half, Q in regs.
// P exchanged via LDS (double-buffered). PV: wave ds=w: 32-d slice x all 64 q.
__global__ __launch_bounds__(512, 2)
void mlstm_mfma(const unsigned short* __restrict__ Qb,
                const unsigned short* __restrict__ Kb,
                const unsigned short* __restrict__ Vt,
                const float* __restrict__ av, const float* __restrict__ Mv,
                const float* __restrict__ nfv, const float* __restrict__ lnw,
                float* __restrict__ out)
{
  __shared__ __align__(16) unsigned short Pls[2][64][72];  // 18.4 KB
  __shared__ float rsb[4][4][16];                          // [ks][qg2][ql]
  __shared__ __align__(16) float Obuf[64][260];            // 66.6 KB

  const int bh = blockIdx.y, b = bh >> 2, h = bh & 3;
  const int ti = (int)gridDim.x - 1 - (int)blockIdx.x;   // big tiles first
  const int i0 = ti * 64;
  const int tid = threadIdx.x;
  const int w = tid >> 6, l = tid & 63;
  const int ks = w & 3, qh = w >> 2;     // QK roles
  const int ds = w;                      // PV role (32-d slice)
  const int lg = l >> 4, ll = l & 15;
  const size_t bhS = (size_t)bh * Sx;

  // Q B-frags (32 q-rows for this wave's q-half), M per q
  bf16x8 qf[2][8];
  float Mq[2];
#pragma unroll
  for (int qg = 0; qg < 2; ++qg) {
    const int qrow = i0 + qh * 32 + qg * 16 + ll;
    const unsigned short* qp = Qb + (bhS + qrow) * DHx + lg * 8;
#pragma unroll
    for (int dstep = 0; dstep < 8; ++dstep)
      qf[qg][dstep] = *(const bf16x8*)(qp + dstep * 32);
    Mq[qg] = Mv[bhS + qrow];
  }

  f32x4 acc[2][4];   // [dt][qg4] : O^T  (d = ds*32+dt*16+lg*4+r, q = qg4*16+ll)
#pragma unroll
  for (int dt = 0; dt < 2; ++dt)
#pragma unroll
    for (int qg = 0; qg < 4; ++qg) acc[dt][qg] = f32x4{0, 0, 0, 0};
  float rsum[2] = {0.f, 0.f};

  const int nt = ti + 1;
  for (int tj = 0; tj < nt; ++tj) {
    const int j0 = tj * 64;
    const int kb = j0 + ks * 16;
    // ---- QK: K frags from L2, 16 MFMA ----
    f32x4 st0 = {0,0,0,0}, st1 = {0,0,0,0};
    {
      const unsigned short* kp = Kb + (bhS + kb + ll) * DHx + lg * 8;
#pragma unroll
      for (int dstep = 0; dstep < 8; ++dstep) {
        bf16x8 kf = *(const bf16x8*)(kp + dstep * 32);
        st0 = __builtin_amdgcn_mfma_f32_16x16x32_bf16(kf, qf[0][dstep], st0, 0, 0, 0);
        st1 = __builtin_amdgcn_mfma_f32_16x16x32_bf16(kf, qf[1][dstep], st1, 0, 0, 0);
      }
    }
    const f32x4 a4 = *(const f32x4*)(av + bhS + kb + lg * 4);
    // ---- transform + P write ----
#pragma unroll
    for (int qg = 0; qg < 2; ++qg) {
      const f32x4 s = qg ? st1 : st0;
      const int qrow = i0 + qh * 32 + qg * 16 + ll;
      const int k0i = kb + lg * 4;
      float p0 = (k0i + 0 <= qrow) ? s[0] * (RSQ * __expf(a4[0] - Mq[qg])) : 0.f;
      float p1 = (k0i + 1 <= qrow) ? s[1] * (RSQ * __expf(a4[1] - Mq[qg])) : 0.f;
      float p2 = (k0i + 2 <= qrow) ? s[2] * (RSQ * __expf(a4[2] - Mq[qg])) : 0.f;
      float p3 = (k0i + 3 <= qrow) ? s[3] * (RSQ * __expf(a4[3] - Mq[qg])) : 0.f;
      rsum[qg] += (p0 + p1) + (p2 + p3);
      uint2 pk = make_uint2(pk2bf(p0, p1), pk2bf(p2, p3));
      *(uint2*)&Pls[tj & 1][qh * 32 + qg * 16 + ll][ks * 16 + lg * 4] = pk;
    }
    __syncthreads();
    // ---- PV: V frags from L2, P frags from LDS, 16 MFMA ----
    const unsigned short* vpb = Vt + ((size_t)bh * DHx + ds * 32 + ll) * Sx + j0 + lg * 8;
#pragma unroll
    for (int kap = 0; kap < 2; ++kap) {
      bf16x8 pf[4];
#pragma unroll
      for (int qg = 0; qg < 4; ++qg)
        pf[qg] = *(const bf16x8*)&Pls[tj & 1][qg * 16 + ll][kap * 32 + lg * 8];
#pragma unroll
      for (int dt = 0; dt < 2; ++dt) {
        bf16x8 vf = *(const bf16x8*)(vpb + (size_t)dt * 16 * Sx + kap * 32);
#pragma unroll
        for (int qg = 0; qg < 4; ++qg)
          acc[dt][qg] = __builtin_amdgcn_mfma_f32_16x16x32_bf16(vf, pf[qg], acc[dt][qg], 0, 0, 0);
      }
    }
  }

  // ---- rsum cross-wave collect ----
#pragma unroll
  for (int qg = 0; qg < 2; ++qg) {
    float r = rsum[qg];
    r += __shfl_xor(r, 16); r += __shfl_xor(r, 32);
    if (l < 16) rsb[ks][qh * 2 + qg][l] = r;
  }
  // ---- acc -> Obuf ----
#pragma unroll
  for (int dt = 0; dt < 2; ++dt)
#pragma unroll
    for (int qg = 0; qg < 4; ++qg)
      *(f32x4*)&Obuf[qg * 16 + ll][ds * 32 + dt * 16 + lg * 4] = acc[dt][qg];
  __syncthreads();

  // ---- epilogue: normalizer + group-LN, thread t: q = t>>3, 32 dims ----
  {
    const int q = tid >> 3, dc = (tid & 7) * 32;
    const int qg2 = q >> 4, ql = q & 15;
    const float rst = rsb[0][qg2][ql] + rsb[1][qg2][ql] + rsb[2][qg2][ql] + rsb[3][qg2][ql];
    const float nf = nfv[bhS + i0 + q];
    const float inv = 1.f / (fmaxf(fabsf(rst), nf) + 1e-6f);
    float xv[32];
    float s1 = 0.f, s2 = 0.f;
#pragma unroll
    for (int jj = 0; jj < 8; ++jj) {
      f32x4 t4 = *(const f32x4*)&Obuf[q][dc + jj * 4];
#pragma unroll
      for (int r = 0; r < 4; ++r) {
        float x = t4[r] * inv;
        xv[jj * 4 + r] = x; s1 += x; s2 += x * x;
      }
    }
    s1 += __shfl_xor(s1, 1); s1 += __shfl_xor(s1, 2); s1 += __shfl_xor(s1, 4);
    s2 += __shfl_xor(s2, 1); s2 += __shfl_xor(s2, 2); s2 += __shfl_xor(s2, 4);
    const float mean = s1 * (1.f / 256.f);
    const float var  = s2 * (1.f / 256.f) - mean * mean;
    const float rstd = rsqrtf(var + 1e-5f);
    float* op = out + ((size_t)b * Sx + i0 + q) * Hx + h * DHx + dc;
#pragma unroll
    for (int jj = 0; jj < 8; ++jj) {
      f32x4 lw = *(const f32x4*)(lnw + h * DHx + dc + jj * 4);
      float4 o;
      o.x = (xv[jj*4+0] - mean) * rstd * (1.f + lw[0]);
      o.y = (xv[jj*4+1] - mean) * rstd * (1.f + lw[1]);
      o.z = (xv[jj*4+2] - mean) * rstd * (1.f + lw[2]);
      o.w = (xv[jj*4+3] - mean) * rstd * (1.f + lw[3]);
      *(float4*)(op + jj * 4) = o;
    }
  }
}

extern "C" void kernel_launch(void* const* d_in, const int* in_sizes, int n_in,
                              void* d_out, int out_size, void* d_ws, size_t ws_size,
                              hipStream_t stream) {
  const float* q   = (const float*)d_in[0];
  const float* k   = (const float*)d_in[1];
  const float* v   = (const float*)d_in[2];
  const float* wi  = (const float*)d_in[3];
  const float* bi  = (const float*)d_in[4];
  const float* wf  = (const float*)d_in[5];
  const float* bf  = (const float*)d_in[6];
  const float* lnw = (const float*)d_in[7];
  float* out = (float*)d_out;
  float* ws  = (float*)d_ws;

  const int G = Bx * NHx * Sx;         // 16384
  float* ig  = ws;
  float* fg  = ws + (size_t)G;
  float* av  = ws + (size_t)2 * G;
  float* Mv  = ws + (size_t)3 * G;
  float* nfv = ws + (size_t)4 * G;
  unsigned short* Qb = (unsigned short*)(ws + (size_t)5 * G);
  unsigned short* Kb = Qb + (size_t)Bx * Sx * Hx;   // 4,194,304 elems
  unsigned short* Vt = Kb + (size_t)Bx * Sx * Hx;
  // total ws use: ~24.3 MB

  gates_kernel<<<Bx * Sx, 256, 0, stream>>>(q, k, v, wi, bi, wf, bf, ig, fg, Qb, Kb);
  scan_kernel<<<Bx * NHx, 256, 0, stream>>>(ig, fg, av, Mv, nfv);
  dim3 gT(Sx / 64, DHx / 64, Bx * NHx);
  vtrans_kernel<<<gT, 256, 0, stream>>>(v, Vt);
  dim3 g4(Sx / 64, Bx * NHx);
  mlstm_mfma<<<g4, 512, 0, stream>>>(Qb, Kb, Vt, av, Mv, nfv, lnw, out);
}